// Round 2
// baseline (12329.387 us; speedup 1.0000x reference)
//
#include <hip/hip_runtime.h>
#include <cstdint>
#include <cstddef>

#define TN   8192
#define DD   512
#define NPER 4
#define KNN  5

// ---------------------------------------------------------------------------
// Sorted-5 insert (ascending by (val, idx) — matches stable argsort ties).
// All indices compile-time after unroll -> stays in registers (rule #20).
// ---------------------------------------------------------------------------
__device__ __forceinline__ void ins5(float v, int ix, float tv[KNN], int ti[KNN]) {
  if (v < tv[4] || (v == tv[4] && ix < ti[4])) {
    tv[4] = v; ti[4] = ix;
#pragma unroll
    for (int s = 4; s > 0; --s) {
      bool sw = (tv[s] < tv[s-1]) || (tv[s] == tv[s-1] && ti[s] < ti[s-1]);
      float nhi = sw ? tv[s-1] : tv[s];
      float nlo = sw ? tv[s]   : tv[s-1];
      int   ihi = sw ? ti[s-1] : ti[s];
      int   ilo = sw ? ti[s]   : ti[s-1];
      tv[s] = nhi; tv[s-1] = nlo;
      ti[s] = ihi; ti[s-1] = ilo;
    }
  }
}

// ---------------------------------------------------------------------------
// Kernel 1: rowsq[r] = sum_d X[r][d]^2   (one wave per row)
// ---------------------------------------------------------------------------
__global__ void sq_kernel(const float* __restrict__ X, float* __restrict__ rowsq) {
  const int row  = (int)blockIdx.x * 4 + ((int)threadIdx.x >> 6);
  const int lane = (int)threadIdx.x & 63;
  const float4* xr = (const float4*)(X + (size_t)row * DD);
  float4 a = xr[lane];
  float4 b = xr[lane + 64];
  float s = a.x*a.x + a.y*a.y + a.z*a.z + a.w*a.w
          + b.x*b.x + b.y*b.y + b.z*b.z + b.w*b.w;
#pragma unroll
  for (int off = 32; off >= 1; off >>= 1) s += __shfl_down(s, off, 64);
  if (lane == 0) rowsq[row] = s;
}

// ---------------------------------------------------------------------------
// Kernel 2: fused 64x4096 dot-tile + per-row running top-5 of
//           key = sq[j] - 2*dot(x_i, x_j)   (monotone in distance, j != i)
// Grid: 256 blocks = 128 row-blocks x 2 column halves. 512 threads (8 waves).
// Thread tile: 4 rows x 8 cols  (top-5 state 40 VGPR, was 80 -> spilled).
// Wave: lane = 32*rh + cg; covers 8 rows (4*rh+q) x 256 cols (8 per cg).
// LDS: A 2*16*68*4 = 8.5KB, B 2*16*260*4 = 33.3KB  (42KB -> 2 blocks/CU)
// ---------------------------------------------------------------------------
#define ROW_FMA(q, as) \
  acc[q][0].x = fmaf(as, b0.x, acc[q][0].x); \
  acc[q][0].y = fmaf(as, b0.y, acc[q][0].y); \
  acc[q][0].z = fmaf(as, b0.z, acc[q][0].z); \
  acc[q][0].w = fmaf(as, b0.w, acc[q][0].w); \
  acc[q][1].x = fmaf(as, b1.x, acc[q][1].x); \
  acc[q][1].y = fmaf(as, b1.y, acc[q][1].y); \
  acc[q][1].z = fmaf(as, b1.z, acc[q][1].z); \
  acc[q][1].w = fmaf(as, b1.w, acc[q][1].w);

__launch_bounds__(512, 4)
__global__ void gemm_top5(const float* __restrict__ X, const float* __restrict__ rowsq,
                          float* __restrict__ topv, int* __restrict__ topi) {
  __shared__ float At[2][16][68];    // [buf][kk][row]
  __shared__ float Bt[2][16][260];   // [buf][kk][col]

  const int tid = (int)threadIdx.x;
  const int cg  = tid & 31;          // col group: 8 cols each
  const int rh  = (tid >> 5) & 1;    // row half within wave
  const int ty  = tid >> 6;          // wave id: row block of 8
  const int bid = (int)blockIdx.x;
  const int rb  = bid >> 1;
  const int cb  = bid & 1;
  const int row0 = rb * 64;
  const int col0 = cb * 4096;

  const int ar = tid >> 2;           // A stage: row 0..63 (tid<256)
  const int am = tid & 3;            // A stage: k-chunk 0..3

  float tv[4][KNN]; int ti[4][KNN];
#pragma unroll
  for (int q = 0; q < 4; ++q) {
#pragma unroll
    for (int s = 0; s < KNN; ++s) { tv[q][s] = 3.4e38f; ti[q][s] = 0x3fffffff; }
  }

  for (int ct = 0; ct < 16; ++ct) {        // column tiles of 256 within this half
    const int jb = col0 + ct * 256;

    float4 acc[4][2];
#pragma unroll
    for (int q = 0; q < 4; ++q) { acc[q][0] = make_float4(0,0,0,0); acc[q][1] = make_float4(0,0,0,0); }

    // pre-stage k-chunk 0 into buffer 0
    if (tid < 256) {
      float4 av = *(const float4*)(X + (size_t)(row0 + ar) * DD + am * 4);
      At[0][4*am+0][ar] = av.x; At[0][4*am+1][ar] = av.y;
      At[0][4*am+2][ar] = av.z; At[0][4*am+3][ar] = av.w;
    }
#pragma unroll
    for (int it = 0; it < 2; ++it) {
      int f = tid + it * 512;
      int j = f >> 2, m = f & 3;
      float4 bvv = *(const float4*)(X + (size_t)(jb + j) * DD + m * 4);
      Bt[0][4*m+0][j] = bvv.x; Bt[0][4*m+1][j] = bvv.y;
      Bt[0][4*m+2][j] = bvv.z; Bt[0][4*m+3][j] = bvv.w;
    }
    __syncthreads();

    for (int ks = 0; ks < 32; ++ks) {      // K = 512 in chunks of 16
      const int cur = ks & 1;
      const int nxt = cur ^ 1;
      const bool pf = (ks + 1) < 32;
      float4 av, bv0, bv1;
      if (pf) {                            // issue next-chunk loads early (G15)
        const int ko = (ks + 1) * 16;
        if (tid < 256)
          av = *(const float4*)(X + (size_t)(row0 + ar) * DD + ko + am * 4);
        { int j = tid >> 2, m = tid & 3;
          bv0 = *(const float4*)(X + (size_t)(jb + j) * DD + ko + m * 4); }
        { int f = tid + 512; int j = f >> 2, m = f & 3;
          bv1 = *(const float4*)(X + (size_t)(jb + j) * DD + ko + m * 4); }
      }

#pragma unroll
      for (int kk = 0; kk < 16; ++kk) {
        const float4 a  = *(const float4*)&At[cur][kk][8*ty + 4*rh];
        const float4 b0 = *(const float4*)&Bt[cur][kk][8*cg];
        const float4 b1 = *(const float4*)&Bt[cur][kk][8*cg+4];
        ROW_FMA(0, a.x) ROW_FMA(1, a.y) ROW_FMA(2, a.z) ROW_FMA(3, a.w)
      }

      if (pf) {                            // write next buffer (disjoint from cur)
        if (tid < 256) {
          At[nxt][4*am+0][ar] = av.x; At[nxt][4*am+1][ar] = av.y;
          At[nxt][4*am+2][ar] = av.z; At[nxt][4*am+3][ar] = av.w;
        }
        { int j = tid >> 2, m = tid & 3;
          Bt[nxt][4*m+0][j] = bv0.x; Bt[nxt][4*m+1][j] = bv0.y;
          Bt[nxt][4*m+2][j] = bv0.z; Bt[nxt][4*m+3][j] = bv0.w; }
        { int f = tid + 512; int j = f >> 2, m = f & 3;
          Bt[nxt][4*m+0][j] = bv1.x; Bt[nxt][4*m+1][j] = bv1.y;
          Bt[nxt][4*m+2][j] = bv1.z; Bt[nxt][4*m+3][j] = bv1.w; }
      }
      __syncthreads();
    }

    // epilogue: turn 32 dots into top-5 candidates (temps die before next ct)
    const float4 sqa = *(const float4*)(rowsq + jb + 8*cg);
    const float4 sqb = *(const float4*)(rowsq + jb + 8*cg + 4);
#pragma unroll
    for (int q = 0; q < 4; ++q) {
      const int gi = row0 + 8*ty + 4*rh + q;
      const int j0 = jb + 8*cg;
      float key;
      key = fmaf(-2.f, acc[q][0].x, sqa.x); if (j0+0 != gi) ins5(key, j0+0, tv[q], ti[q]);
      key = fmaf(-2.f, acc[q][0].y, sqa.y); if (j0+1 != gi) ins5(key, j0+1, tv[q], ti[q]);
      key = fmaf(-2.f, acc[q][0].z, sqa.z); if (j0+2 != gi) ins5(key, j0+2, tv[q], ti[q]);
      key = fmaf(-2.f, acc[q][0].w, sqa.w); if (j0+3 != gi) ins5(key, j0+3, tv[q], ti[q]);
      key = fmaf(-2.f, acc[q][1].x, sqb.x); if (j0+4 != gi) ins5(key, j0+4, tv[q], ti[q]);
      key = fmaf(-2.f, acc[q][1].y, sqb.y); if (j0+5 != gi) ins5(key, j0+5, tv[q], ti[q]);
      key = fmaf(-2.f, acc[q][1].z, sqb.z); if (j0+6 != gi) ins5(key, j0+6, tv[q], ti[q]);
      key = fmaf(-2.f, acc[q][1].w, sqb.w); if (j0+7 != gi) ins5(key, j0+7, tv[q], ti[q]);
    }
  }

  // butterfly merge across the 32 lanes (cg) that share this row-set.
  // d<32 never flips the rh bit, so rows stay aligned.
#pragma unroll
  for (int d = 1; d < 32; d <<= 1) {
#pragma unroll
    for (int q = 0; q < 4; ++q) {
      float ov[KNN]; int oi[KNN];
#pragma unroll
      for (int s = 0; s < KNN; ++s) {      // snapshot BEFORE mutating
        ov[s] = __shfl_xor(tv[q][s], d, 64);
        oi[s] = __shfl_xor(ti[q][s], d, 64);
      }
#pragma unroll
      for (int s = 0; s < KNN; ++s) ins5(ov[s], oi[s], tv[q], ti[q]);
    }
  }

  if (cg == 0) {
#pragma unroll
    for (int q = 0; q < 4; ++q) {
      const int gi = row0 + 8*ty + 4*rh + q;
#pragma unroll
      for (int s = 0; s < KNN; ++s) {
        topv[(gi * 2 + cb) * KNN + s] = tv[q][s];
        topi[(gi * 2 + cb) * KNN + s] = ti[q][s];
      }
    }
  }
}

// ---------------------------------------------------------------------------
// Kernel 3: merge the two column-half top-5 lists -> final nn[T][5] (sorted)
// ---------------------------------------------------------------------------
__global__ void merge_nn(const float* __restrict__ topv, const int* __restrict__ topi,
                         int* __restrict__ nn) {
  const int i = (int)blockIdx.x * 256 + (int)threadIdx.x;
  float tv[KNN]; int ti[KNN];
#pragma unroll
  for (int s = 0; s < KNN; ++s) { tv[s] = topv[(i*2+0)*KNN + s]; ti[s] = topi[(i*2+0)*KNN + s]; }
#pragma unroll
  for (int s = 0; s < KNN; ++s) ins5(topv[(i*2+1)*KNN + s], topi[(i*2+1)*KNN + s], tv, ti);
#pragma unroll
  for (int s = 0; s < KNN; ++s) nn[i*KNN + s] = ti[s];
}

// ---------------------------------------------------------------------------
// Kernel 4: synthesis  out[i*4+p] = x_i + g * (x_nn - x_i)
// ---------------------------------------------------------------------------
__global__ void synth_kernel(const float* __restrict__ X, const int* __restrict__ nn,
                             const float* __restrict__ gaps, const int* __restrict__ choice,
                             float* __restrict__ out) {
  const float4* X4 = (const float4*)X;
  float4* O4 = (float4*)out;
  const int base = (int)blockIdx.x * 256 + (int)threadIdx.x;
#pragma unroll
  for (int it = 0; it < 8; ++it) {
    const int f    = base + it * (2048 * 256);
    const int orow = f >> 7;            // output row (= i*NPER + p)
    const int d4   = f & 127;           // float4 within row
    const int i    = orow >> 2;
    const int ch   = choice[orow];
    const int nr   = nn[i * KNN + ch];
    const float g  = gaps[orow];
    const float4 xi = X4[(size_t)i  * 128 + d4];
    const float4 xn = X4[(size_t)nr * 128 + d4];
    float4 r;
    r.x = fmaf(g, xn.x - xi.x, xi.x);
    r.y = fmaf(g, xn.y - xi.y, xi.y);
    r.z = fmaf(g, xn.z - xi.z, xi.z);
    r.w = fmaf(g, xn.w - xi.w, xi.w);
    O4[(size_t)orow * 128 + d4] = r;
  }
}

// ---------------------------------------------------------------------------
extern "C" void kernel_launch(void* const* d_in, const int* in_sizes, int n_in,
                              void* d_out, int out_size, void* d_ws, size_t ws_size,
                              hipStream_t stream) {
  const float* X      = (const float*)d_in[0];   // [8192, 512] fp32
  const float* gaps   = (const float*)d_in[1];   // [8192, 4]  fp32
  const int*   choice = (const int*)  d_in[2];   // [8192, 4]  int32 (values 0..4)
  float* out = (float*)d_out;

  // workspace layout (fp32 elems): sq[8192] | topv[8192*2*5] | topi | nn  (~852 KB)
  float* rowsq = (float*)d_ws;
  float* topv  = rowsq + TN;
  int*   topi  = (int*)(topv + (size_t)TN * 2 * KNN);
  int*   nn    = (int*)(topi + (size_t)TN * 2 * KNN);

  sq_kernel  <<<TN / 4,  256, 0, stream>>>(X, rowsq);
  gemm_top5  <<<256,     512, 0, stream>>>(X, rowsq, topv, topi);
  merge_nn   <<<TN / 256,256, 0, stream>>>(topv, topi, nn);
  synth_kernel<<<2048,   256, 0, stream>>>(X, nn, gaps, choice, out);
}

// Round 3
// 891.516 us; speedup vs baseline: 13.8297x; 13.8297x over previous
//
#include <hip/hip_runtime.h>
#include <cstdint>
#include <cstddef>

#define TN   8192
#define DD   512
#define NPER 4
#define KNN  5

typedef _Float16 f16x8 __attribute__((ext_vector_type(8)));
typedef float    f32x4 __attribute__((ext_vector_type(4)));

// key = sq_row - 2 * acc / 4096^2  ->  fmaf(acc, -2^-23, sq_row)
#define KSCALE (-1.1920928955078125e-07f)

// ---------------------------------------------------------------------------
// Sorted-5 insert, ascending by (val, idx) — matches stable argsort ties.
// ---------------------------------------------------------------------------
__device__ __forceinline__ void ins5(float v, int ix, float tv[KNN], int ti[KNN]) {
  if (v < tv[4] || (v == tv[4] && ix < ti[4])) {
    tv[4] = v; ti[4] = ix;
#pragma unroll
    for (int s = 4; s > 0; --s) {
      bool sw = (tv[s] < tv[s-1]) || (tv[s] == tv[s-1] && ti[s] < ti[s-1]);
      float nhi = sw ? tv[s-1] : tv[s];
      float nlo = sw ? tv[s]   : tv[s-1];
      int   ihi = sw ? ti[s-1] : ti[s];
      int   ilo = sw ? ti[s]   : ti[s-1];
      tv[s] = nhi; tv[s-1] = nlo;
      ti[s] = ihi; ti[s-1] = ilo;
    }
  }
}

__device__ __forceinline__ void gll16(const void* g, void* l) {
  __builtin_amdgcn_global_load_lds(
      (const __attribute__((address_space(1))) void*)g,
      (__attribute__((address_space(3))) void*)l, 16, 0, 0);
}

// ---------------------------------------------------------------------------
// Kernel 0: hi/lo fp16 split of X*4096.  hi = f16(4096x), lo = f16(4096x - hi)
// ---------------------------------------------------------------------------
__global__ void prep_kernel(const float* __restrict__ X,
                            _Float16* __restrict__ H, _Float16* __restrict__ L) {
  const int g = (int)blockIdx.x * 256 + (int)threadIdx.x;   // 0..524287 (8-elem groups)
  const float4 x0 = ((const float4*)X)[2*g];
  const float4 x1 = ((const float4*)X)[2*g + 1];
  float xs[8] = {x0.x, x0.y, x0.z, x0.w, x1.x, x1.y, x1.z, x1.w};
  f16x8 h8, l8;
#pragma unroll
  for (int j = 0; j < 8; ++j) {
    float s = xs[j] * 4096.f;
    _Float16 h = (_Float16)s;
    h8[j] = h;
    l8[j] = (_Float16)(s - (float)h);
  }
  ((f16x8*)H)[g] = h8;
  ((f16x8*)L)[g] = l8;
}

// ---------------------------------------------------------------------------
// Kernel 1: rowsq[r] = sum_d X[r][d]^2   (one wave per row) — exact fp32 X
// ---------------------------------------------------------------------------
__global__ void sq_kernel(const float* __restrict__ X, float* __restrict__ rowsq) {
  const int row  = (int)blockIdx.x * 4 + ((int)threadIdx.x >> 6);
  const int lane = (int)threadIdx.x & 63;
  const float4* xr = (const float4*)(X + (size_t)row * DD);
  float4 a = xr[lane];
  float4 b = xr[lane + 64];
  float s = a.x*a.x + a.y*a.y + a.z*a.z + a.w*a.w
          + b.x*b.x + b.y*b.y + b.z*b.z + b.w*b.w;
#pragma unroll
  for (int off = 32; off >= 1; off >>= 1) s += __shfl_down(s, off, 64);
  if (lane == 0) rowsq[row] = s;
}

// ---------------------------------------------------------------------------
// Kernel 2: fp16 split-MFMA GEMM (K = 3*512: HH + HL + LH) with fused
// column-mode top-5 selection (d2 symmetric -> select per center column).
// Grid: 1024 = 64 row-blocks x 16 col-strips(512). Block: 256 thr = 4 waves.
// Block tile 128x128; wave (wr,wc) owns 64x64 = 4x4 frags of 16x16x32 f16.
// LDS: 2 bufs x (A 8KB + B 8KB) = 32 KB, staged by global_load_lds width 16.
// C layout (m89): col = lane&15, row = 4*(lane>>4) + reg.
// Partials: per col, per (row-block, wr): top5 of 64 rows -> [8192][128][5].
// ---------------------------------------------------------------------------
__global__ void gemm_mfma(const _Float16* __restrict__ H, const _Float16* __restrict__ L,
                          const float* __restrict__ rowsq, float* __restrict__ partials) {
  __shared__ __align__(16) char smem[32768];
  const int tid  = (int)threadIdx.x;
  const int lane = tid & 63;
  const int w    = tid >> 6;          // wave 0..3
  const int wr   = w >> 1, wc = w & 1;
  const int bid  = (int)blockIdx.x;
  const int rb   = bid & 63;
  const int cs   = bid >> 6;          // 0..15
  const int row0 = rb * 128;
  const int lgrp = lane >> 4;         // 0..3  (k-group / C row-group)
  const int lidx = lane & 15;         // A-row / B-col / C-col within frag

  // row sq values for this lane's 16 C-rows (fixed for the whole block)
  float sqr[16];
#pragma unroll
  for (int rt = 0; rt < 4; ++rt)
#pragma unroll
    for (int q = 0; q < 4; ++q)
      sqr[rt*4+q] = rowsq[row0 + wr*64 + rt*16 + lgrp*4 + q];

  const int srw = (lane >> 2);        // staging: row-within-16 chunk
  const int skc = (lane & 3) * 8;     // staging: k offset (f16 elems)

#define STAGE(buf, ksv) do {                                                   \
    const int seg_ = (ksv) >> 4;                                               \
    const int kk_  = ((ksv) & 15) * 32;                                        \
    const _Float16* sA_ = (seg_ == 2) ? L : H;                                 \
    const _Float16* sB_ = (seg_ == 1) ? L : H;                                 \
    char* ab_ = smem + (buf)*16384 + 2048*w;                                   \
    char* bb_ = ab_ + 8192;                                                    \
    gll16(sA_ + (size_t)(row0 + 32*w      + srw)*DD + kk_ + skc, ab_);         \
    gll16(sA_ + (size_t)(row0 + 32*w + 16 + srw)*DD + kk_ + skc, ab_ + 1024);  \
    gll16(sB_ + (size_t)(jb   + 32*w      + srw)*DD + kk_ + skc, bb_);         \
    gll16(sB_ + (size_t)(jb   + 32*w + 16 + srw)*DD + kk_ + skc, bb_ + 1024);  \
  } while (0)

  for (int ct = 0; ct < 4; ++ct) {            // 4 col-tiles of 128 per strip
    const int jb = cs * 512 + ct * 128;
    f32x4 acc[4][4] = {};

    STAGE(0, 0);
    __syncthreads();

    for (int ks = 0; ks < 48; ++ks) {         // K = 1536 in chunks of 32
      const int cur = ks & 1;
      if (ks < 47) STAGE(cur ^ 1, ks + 1);    // prefetch into other buffer

      const char* Ab = smem + cur*16384;
      const char* Bb = Ab + 8192;
      const int lao = (wr*64 + lidx)*64 + lgrp*16;
      const int lbo = (wc*64 + lidx)*64 + lgrp*16;
      f16x8 af[4], bf[4];
#pragma unroll
      for (int t = 0; t < 4; ++t) {
        af[t] = *(const f16x8*)(Ab + lao + t*1024);
        bf[t] = *(const f16x8*)(Bb + lbo + t*1024);
      }
#pragma unroll
      for (int rt = 0; rt < 4; ++rt)
#pragma unroll
        for (int cf = 0; cf < 4; ++cf)
          acc[rt][cf] = __builtin_amdgcn_mfma_f32_16x16x32_f16(af[rt], bf[cf], acc[rt][cf], 0, 0, 0);

      __syncthreads();                        // next buffer staged + cur consumed
    }

    // ---- fused selection epilogue (column-mode) ----
#pragma unroll
    for (int cf = 0; cf < 4; ++cf) {
      const int jc = jb + wc*64 + cf*16 + lidx;   // this lane's center column
      float tv[KNN]; int ti[KNN];
#pragma unroll
      for (int s = 0; s < KNN; ++s) { tv[s] = 3.4e38f; ti[s] = 0x3fffffff; }
#pragma unroll
      for (int rt = 0; rt < 4; ++rt) {
#pragma unroll
        for (int q = 0; q < 4; ++q) {
          const int r = row0 + wr*64 + rt*16 + lgrp*4 + q;
          const float key = fmaf(acc[rt][cf][q], KSCALE, sqr[rt*4+q]);
          if (r != jc) ins5(key, r, tv, ti);
        }
      }
      // merge the 4 lanes (same col, different row-groups): d = 16, 32
#pragma unroll
      for (int d = 16; d <= 32; d <<= 1) {
        float ov[KNN]; int oi[KNN];
#pragma unroll
        for (int s = 0; s < KNN; ++s) {
          ov[s] = __shfl_xor(tv[s], d, 64);
          oi[s] = __shfl_xor(ti[s], d, 64);
        }
#pragma unroll
        for (int s = 0; s < KNN; ++s) ins5(ov[s], oi[s], tv, ti);
      }
      if (lane < 16) {                        // one writer per column
        float* pw = partials + ((size_t)jc * 128 + (rb*2 + wr)) * 10;
#pragma unroll
        for (int s = 0; s < KNN; ++s) { pw[2*s] = tv[s]; ((int*)pw)[2*s+1] = ti[s]; }
      }
    }
  }
#undef STAGE
}

// ---------------------------------------------------------------------------
// Kernel 3: fold 128 partial top-5 lists per column -> nn[T][5] (sorted)
// One wave per column.
// ---------------------------------------------------------------------------
__global__ void merge_nn(const float* __restrict__ parts, int* __restrict__ nn) {
  const int j    = (int)blockIdx.x * 4 + ((int)threadIdx.x >> 6);
  const int lane = (int)threadIdx.x & 63;
  float tv[KNN]; int ti[KNN];
#pragma unroll
  for (int s = 0; s < KNN; ++s) { tv[s] = 3.4e38f; ti[s] = 0x3fffffff; }
  const float* p0 = parts + ((size_t)j * 128 + lane) * 10;
  const float* p1 = parts + ((size_t)j * 128 + lane + 64) * 10;
#pragma unroll
  for (int s = 0; s < KNN; ++s) ins5(p0[2*s], ((const int*)p0)[2*s+1], tv, ti);
#pragma unroll
  for (int s = 0; s < KNN; ++s) ins5(p1[2*s], ((const int*)p1)[2*s+1], tv, ti);
#pragma unroll
  for (int d = 1; d < 64; d <<= 1) {
    float ov[KNN]; int oi[KNN];
#pragma unroll
    for (int s = 0; s < KNN; ++s) {
      ov[s] = __shfl_xor(tv[s], d, 64);
      oi[s] = __shfl_xor(ti[s], d, 64);
    }
#pragma unroll
    for (int s = 0; s < KNN; ++s) ins5(ov[s], oi[s], tv, ti);
  }
  if (lane == 0) {
#pragma unroll
    for (int s = 0; s < KNN; ++s) nn[j*KNN + s] = ti[s];
  }
}

// ---------------------------------------------------------------------------
// Kernel 4: synthesis  out[i*4+p] = x_i + g * (x_nn - x_i)
// ---------------------------------------------------------------------------
__global__ void synth_kernel(const float* __restrict__ X, const int* __restrict__ nn,
                             const float* __restrict__ gaps, const int* __restrict__ choice,
                             float* __restrict__ out) {
  const float4* X4 = (const float4*)X;
  float4* O4 = (float4*)out;
  const int base = (int)blockIdx.x * 256 + (int)threadIdx.x;
#pragma unroll
  for (int it = 0; it < 8; ++it) {
    const int f    = base + it * (2048 * 256);
    const int orow = f >> 7;
    const int d4   = f & 127;
    const int i    = orow >> 2;
    const int ch   = choice[orow];
    const int nr   = nn[i * KNN + ch];
    const float g  = gaps[orow];
    const float4 xi = X4[(size_t)i  * 128 + d4];
    const float4 xn = X4[(size_t)nr * 128 + d4];
    float4 r;
    r.x = fmaf(g, xn.x - xi.x, xi.x);
    r.y = fmaf(g, xn.y - xi.y, xi.y);
    r.z = fmaf(g, xn.z - xi.z, xi.z);
    r.w = fmaf(g, xn.w - xi.w, xi.w);
    O4[(size_t)orow * 128 + d4] = r;
  }
}

// ---------------------------------------------------------------------------
// d_out (64 MB) doubles as scratch: H[8MB] | L[8MB] | partials[42MB] — synth
// fully rewrites d_out last, so this is safe and leaves d_ws tiny (~200 KB).
// ---------------------------------------------------------------------------
extern "C" void kernel_launch(void* const* d_in, const int* in_sizes, int n_in,
                              void* d_out, int out_size, void* d_ws, size_t ws_size,
                              hipStream_t stream) {
  const float* X      = (const float*)d_in[0];
  const float* gaps   = (const float*)d_in[1];
  const int*   choice = (const int*)  d_in[2];
  float* out = (float*)d_out;

  _Float16* Hbuf = (_Float16*)d_out;                        // [0, 8M)
  _Float16* Lbuf = (_Float16*)((char*)d_out + 8388608);     // [8M, 16M)
  float*    parts = (float*)((char*)d_out + 16777216);      // [16M, 58M)

  float* rowsq = (float*)d_ws;                              // 32 KB
  int*   nn    = (int*)((char*)d_ws + TN * 4);              // 160 KB

  prep_kernel <<<2048, 256, 0, stream>>>(X, Hbuf, Lbuf);
  sq_kernel   <<<2048, 256, 0, stream>>>(X, rowsq);
  gemm_mfma   <<<1024, 256, 0, stream>>>(Hbuf, Lbuf, rowsq, parts);
  merge_nn    <<<2048, 256, 0, stream>>>(parts, nn);
  synth_kernel<<<2048, 256, 0, stream>>>(X, nn, gaps, choice, out);
}